// Round 1
// baseline (21349.113 us; speedup 1.0000x reference)
//
#include <hip/hip_runtime.h>
#include <hip/hip_bf16.h>
#include <hip/hip_cooperative_groups.h>

namespace cg = cooperative_groups;

using f32x4  = __attribute__((ext_vector_type(4))) float;
using bf16x8 = __attribute__((ext_vector_type(8))) __bf16;

#define T_DIM 512
#define B_DIM 64
#define D_DIM 1024
#define H_DIM 1024
#define G_DIM 4096   // 4*H

// ---------------------------------------------------------------------------
// fp32 -> bf16 conversion (vectorized 8/thread)
// ---------------------------------------------------------------------------
__global__ void f32_to_bf16_kernel(const float* __restrict__ src,
                                   __bf16* __restrict__ dst, long n) {
    long i = ((long)blockIdx.x * blockDim.x + threadIdx.x) * 8;
    if (i + 8 <= n) {
        f32x4 a = *(const f32x4*)(src + i);
        f32x4 b = *(const f32x4*)(src + i + 4);
        bf16x8 o;
        o[0] = (__bf16)a[0]; o[1] = (__bf16)a[1];
        o[2] = (__bf16)a[2]; o[3] = (__bf16)a[3];
        o[4] = (__bf16)b[0]; o[5] = (__bf16)b[1];
        o[6] = (__bf16)b[2]; o[7] = (__bf16)b[3];
        *(bf16x8*)(dst + i) = o;
    }
}

// ---------------------------------------------------------------------------
// Phase 1: xg[M][4096] = A[M][1024](bf16) @ W[4096][1024]^T (bf16) + bias
// m97-style: 128x128 tile, BK=64, global_load_lds width=16, 16x16x32 bf16 MFMA.
// M = tc*64 (multiple of 128 since tc even); no bounds checks needed.
// ---------------------------------------------------------------------------
#define BM 128
#define BN 128
#define BK 64

__global__ __launch_bounds__(256) void gemm_xg_kernel(
    const __bf16* __restrict__ A,    // [M][1024]
    const __bf16* __restrict__ W,    // [4096][1024]
    const float* __restrict__ bias,  // [4096]
    float* __restrict__ C,           // [M][4096]
    int M)
{
    (void)M;
    __shared__ __bf16 sA[BM * BK];
    __shared__ __bf16 sB[BN * BK];

    const int tid = threadIdx.x;
    const int wv  = tid >> 6;        // wave 0..3
    const int l   = tid & 63;
    const int wy  = wv >> 1, wx = wv & 1;
    const int bm  = blockIdx.y * BM;
    const int bn  = blockIdx.x * BN;
    const int n   = l & 15;          // MFMA lane col/row-in-tile
    const int q   = l >> 4;          // quad

    // staging: each (wave, issue) covers 8 rows of 64 bf16 (1 KiB), lane i ->
    // row i>>3, k-offset (i&7)*8.  LDS dest must be wave-uniform base.
    const int srow  = l >> 3;
    const int skoff = (l & 7) * 8;

    f32x4 acc[4][4];
    #pragma unroll
    for (int mt = 0; mt < 4; ++mt)
        #pragma unroll
        for (int nt = 0; nt < 4; ++nt)
            acc[mt][nt] = (f32x4){0.f, 0.f, 0.f, 0.f};

    for (int kt = 0; kt < D_DIM / BK; ++kt) {
        const int k0 = kt * BK;
        #pragma unroll
        for (int j = 0; j < 4; ++j) {
            const int rbase = (j * 4 + wv) * 8;
            const __bf16* ga = A + (long)(bm + rbase + srow) * D_DIM + k0 + skoff;
            const __bf16* gb = W + (long)(bn + rbase + srow) * D_DIM + k0 + skoff;
            __builtin_amdgcn_global_load_lds(
                (const __attribute__((address_space(1))) void*)ga,
                (__attribute__((address_space(3))) void*)(sA + rbase * BK), 16, 0, 0);
            __builtin_amdgcn_global_load_lds(
                (const __attribute__((address_space(1))) void*)gb,
                (__attribute__((address_space(3))) void*)(sB + rbase * BK), 16, 0, 0);
        }
        __syncthreads();   // drains vmcnt for global_load_lds

        #pragma unroll
        for (int ks = 0; ks < 2; ++ks) {
            bf16x8 af[4], bf[4];
            #pragma unroll
            for (int mt = 0; mt < 4; ++mt) {
                int row = wy * 64 + mt * 16 + n;
                af[mt] = *(const bf16x8*)(sA + row * BK + ks * 32 + q * 8);
            }
            #pragma unroll
            for (int nt = 0; nt < 4; ++nt) {
                int col = wx * 64 + nt * 16 + n;
                bf[nt] = *(const bf16x8*)(sB + col * BK + ks * 32 + q * 8);
            }
            #pragma unroll
            for (int mt = 0; mt < 4; ++mt)
                #pragma unroll
                for (int nt = 0; nt < 4; ++nt)
                    acc[mt][nt] = __builtin_amdgcn_mfma_f32_16x16x32_bf16(
                        af[mt], bf[nt], acc[mt][nt], 0, 0, 0);
        }
        __syncthreads();
    }

    // epilogue: C/D layout col = lane&15, row = quad*4 + reg
    #pragma unroll
    for (int nt = 0; nt < 4; ++nt) {
        int col = bn + wx * 64 + nt * 16 + n;
        float b = bias[col];
        #pragma unroll
        for (int mt = 0; mt < 4; ++mt) {
            #pragma unroll
            for (int r = 0; r < 4; ++r) {
                int row = bm + wy * 64 + mt * 16 + q * 4 + r;
                C[(long)row * G_DIM + col] = acc[mt][nt][r] + b;
            }
        }
    }
}

// ---------------------------------------------------------------------------
// Phase 2: persistent cooperative scan.
// 256 wgs x 256 thr. wg owns 4 hidden units -> 16 gate cols {g*1024+u0+u}.
// Wh slice held in REGISTERS (32 x bf16x8 = 128 VGPRs/lane) -> no LDS in the
// K-loop, immune to L2 invalidation from grid.sync fences.
// Wave wv = batch rows [wv*16, wv*16+16). One grid.sync per step; h state
// double-buffered bf16 (parity gt&1) so reads/writes never collide.
// ---------------------------------------------------------------------------
__global__ __launch_bounds__(256, 1) void lstm_scan_kernel(
    const __bf16* __restrict__ Whb,   // [4096][1024] bf16
    const float* __restrict__ xg,     // [tc][64][4096] fp32 (chunk-local)
    const float* __restrict__ mask,   // [512][64]
    float* __restrict__ cst,          // [64][1024] fp32 state
    __bf16* __restrict__ hbuf,        // [2][64][1024] bf16 state
    float* __restrict__ out,          // [512][64][1024]
    int t0, int tc)
{
    __shared__ float sg[4][16 * 17];  // per-wave gate exchange, padded

    const int tid  = threadIdx.x;
    const int wgid = blockIdx.x;      // 0..255
    const int u0   = wgid * 4;        // first hidden unit of this wg
    const int wv   = tid >> 6;
    const int l    = tid & 63;
    const int n    = l & 15;          // MFMA col (= gate*4 + unit)
    const int q    = l >> 4;          // quad
    const int colg = ((n >> 2) << 10) + u0 + (n & 3);  // gate column in [0,4096)

    // B fragments (Wh slice) in registers, loaded once.
    bf16x8 breg[32];
    {
        const __bf16* wrow = Whb + (long)colg * H_DIM + q * 8;
        #pragma unroll
        for (int ks = 0; ks < 32; ++ks)
            breg[ks] = *(const bf16x8*)(wrow + ks * 32);
    }

    const int rowA = wv * 16 + n;     // batch row for A fragment
    const int rloc = l >> 2;          // elementwise: row within wave
    const int ui   = l & 3;           // elementwise: unit within wg
    const int rb   = wv * 16 + rloc;  // global batch row
    const int uu   = u0 + ui;         // global hidden unit

    cg::grid_group grid = cg::this_grid();

    for (int t = 0; t < tc; ++t) {
        const int gt = t0 + t;
        const __bf16* hread = hbuf + (long)(gt & 1) * (B_DIM * H_DIM);
        __bf16* hwrite = hbuf + (long)((gt + 1) & 1) * (B_DIM * H_DIM);

        // independent scalar loads issued before the MFMA loop (latency overlap)
        const float* xgrow = xg + ((long)t * B_DIM + rb) * G_DIM;
        float xgv0 = xgrow[uu];
        float xgv1 = xgrow[H_DIM + uu];
        float xgv2 = xgrow[2 * H_DIM + uu];
        float xgv3 = xgrow[3 * H_DIM + uu];
        float mk    = mask[gt * B_DIM + rb];
        float c_old = cst[rb * H_DIM + uu];
        float h_old = (gt == 0) ? 0.0f
                                : out[((long)(gt - 1) * B_DIM + rb) * H_DIM + uu];

        // gates[rowA][colg] partial = sum_k h[rowA][k] * Wh[colg][k]
        const __bf16* hrow = hread + (long)rowA * H_DIM + q * 8;
        f32x4 ac0 = {0.f, 0.f, 0.f, 0.f};
        f32x4 ac1 = {0.f, 0.f, 0.f, 0.f};
        #pragma unroll
        for (int ks = 0; ks < 32; ks += 2) {
            bf16x8 a0 = *(const bf16x8*)(hrow + ks * 32);
            bf16x8 a1 = *(const bf16x8*)(hrow + (ks + 1) * 32);
            ac0 = __builtin_amdgcn_mfma_f32_16x16x32_bf16(a0, breg[ks],     ac0, 0, 0, 0);
            ac1 = __builtin_amdgcn_mfma_f32_16x16x32_bf16(a1, breg[ks + 1], ac1, 0, 0, 0);
        }
        f32x4 acc = ac0 + ac1;

        // write gates to per-wave LDS (C/D layout row=q*4+r, col=n)
        #pragma unroll
        for (int r = 0; r < 4; ++r)
            sg[wv][(q * 4 + r) * 17 + n] = acc[r];
        __syncthreads();

        // elementwise cell update: lane -> (batch rb, unit uu)
        float ig = xgv0 + sg[wv][rloc * 17 + 0  + ui];
        float fg = xgv1 + sg[wv][rloc * 17 + 4  + ui];
        float og = xgv2 + sg[wv][rloc * 17 + 8  + ui];
        float gg = xgv3 + sg[wv][rloc * 17 + 12 + ui];

        float i_s = 1.0f / (1.0f + __expf(-ig));
        float f_s = 1.0f / (1.0f + __expf(-fg));
        float o_s = 1.0f / (1.0f + __expf(-og));
        float g_t = tanhf(gg);
        float c_new = f_s * c_old + i_s * g_t;
        float h_new = o_s * tanhf(c_new);
        float c_f = mk * c_new + (1.0f - mk) * c_old;
        float h_f = mk * h_new + (1.0f - mk) * h_old;

        cst[rb * H_DIM + uu] = c_f;
        hwrite[rb * H_DIM + uu] = (__bf16)h_f;
        out[((long)gt * B_DIM + rb) * H_DIM + uu] = h_f;

        grid.sync();   // release h_t device-wide; acquire for next step's reads
    }
}

// ---------------------------------------------------------------------------
// Host side: workspace layout + chunked pipeline.
//   [Whb 8MiB][Wxb 8MiB][hbuf 256KiB x2][cst 256KiB][xb chunk][xg chunk]
// Chunk size Tc derived from ws_size (deterministic per call -> graph safe).
// ---------------------------------------------------------------------------
extern "C" void kernel_launch(void* const* d_in, const int* in_sizes, int n_in,
                              void* d_out, int out_size, void* d_ws, size_t ws_size,
                              hipStream_t stream)
{
    (void)in_sizes; (void)n_in; (void)out_size;
    const float* x     = (const float*)d_in[0];  // [512][64][1024]
    const float* xmask = (const float*)d_in[1];  // [512][64]
    const float* Wx    = (const float*)d_in[2];  // [4096][1024]
    const float* bx    = (const float*)d_in[3];  // [4096]
    const float* Wh    = (const float*)d_in[4];  // [4096][1024]
    float* out = (float*)d_out;

    char* ws = (char*)d_ws;
    __bf16* Whb = (__bf16*)(ws);
    __bf16* Wxb = (__bf16*)(ws + 8388608);
    __bf16* hb  = (__bf16*)(ws + 16777216);            // 2 x 131072 B
    float*  cst = (float*)(ws + 16777216 + 262144);    // 262144 B
    char* dyn   = ws + 16777216 + 524288;

    long avail = (long)ws_size - (16777216L + 524288L);
    const long per_t = (long)B_DIM * D_DIM * 2 + (long)B_DIM * G_DIM * 4;
    long Tc = avail > 0 ? avail / per_t : 2;
    if (Tc > T_DIM) Tc = T_DIM;
    Tc &= ~1L;
    if (Tc < 2) Tc = 2;

    __bf16* xb = (__bf16*)dyn;
    float*  xg = (float*)(dyn + Tc * (long)B_DIM * D_DIM * 2);

    // zero h0/c0 state
    hipMemsetAsync(ws + 16777216, 0, 524288, stream);

    // convert weights once per call
    {
        long nw = (long)G_DIM * D_DIM;               // 4194304
        int nb = (int)(nw / 8 / 256);                // 2048
        f32_to_bf16_kernel<<<nb, 256, 0, stream>>>(Wx, Wxb, nw);
        f32_to_bf16_kernel<<<nb, 256, 0, stream>>>(Wh, Whb, nw);
    }

    for (int t0 = 0; t0 < T_DIM; t0 += (int)Tc) {
        int tc = (int)((T_DIM - t0 < Tc) ? (long)(T_DIM - t0) : Tc);

        long nx = (long)tc * B_DIM * D_DIM;
        f32_to_bf16_kernel<<<(int)(nx / 8 / 256), 256, 0, stream>>>(
            x + (long)t0 * B_DIM * D_DIM, xb, nx);

        dim3 gg(G_DIM / BN, (tc * B_DIM) / BM);
        gemm_xg_kernel<<<gg, 256, 0, stream>>>(xb, Wxb, bx, xg, tc * B_DIM);

        const __bf16* Whb_a = Whb;
        const float*  xg_a  = xg;
        const float*  mask_a = xmask;
        float*  cst_a = cst;
        __bf16* hb_a  = hb;
        float*  out_a = out;
        int t0_a = t0, tc_a = tc;
        void* args[] = {(void*)&Whb_a, (void*)&xg_a, (void*)&mask_a,
                        (void*)&cst_a, (void*)&hb_a, (void*)&out_a,
                        (void*)&t0_a, (void*)&tc_a};
        hipLaunchCooperativeKernel((void*)lstm_scan_kernel, dim3(256), dim3(256),
                                   args, 0, stream);
    }
}

// Round 2
// 12280.341 us; speedup vs baseline: 1.7385x; 1.7385x over previous
//
#include <hip/hip_runtime.h>
#include <hip/hip_bf16.h>

using f32x4  = __attribute__((ext_vector_type(4))) float;
using bf16x8 = __attribute__((ext_vector_type(8))) __bf16;

#define T_DIM 512
#define B_DIM 64
#define D_DIM 1024
#define H_DIM 1024
#define G_DIM 4096   // 4*H
#define NWG   256    // workgroups in the scan kernel

// ---------------------------------------------------------------------------
// fp32 -> bf16 conversion (vectorized 8/thread)
// ---------------------------------------------------------------------------
__global__ void f32_to_bf16_kernel(const float* __restrict__ src,
                                   __bf16* __restrict__ dst, long n) {
    long i = ((long)blockIdx.x * blockDim.x + threadIdx.x) * 8;
    if (i + 8 <= n) {
        f32x4 a = *(const f32x4*)(src + i);
        f32x4 b = *(const f32x4*)(src + i + 4);
        bf16x8 o;
        o[0] = (__bf16)a[0]; o[1] = (__bf16)a[1];
        o[2] = (__bf16)a[2]; o[3] = (__bf16)a[3];
        o[4] = (__bf16)b[0]; o[5] = (__bf16)b[1];
        o[6] = (__bf16)b[2]; o[7] = (__bf16)b[3];
        *(bf16x8*)(dst + i) = o;
    }
}

// ---------------------------------------------------------------------------
// Phase 1: xg[M][4096] = A[M][1024](bf16) @ W[4096][1024]^T (bf16) + bias
// m97-style: 128x128 tile, BK=64, global_load_lds width=16, 16x16x32 bf16 MFMA.
// ---------------------------------------------------------------------------
#define BM 128
#define BN 128
#define BK 64

__global__ __launch_bounds__(256) void gemm_xg_kernel(
    const __bf16* __restrict__ A,    // [M][1024]
    const __bf16* __restrict__ W,    // [4096][1024]
    const float* __restrict__ bias,  // [4096]
    float* __restrict__ C,           // [M][4096]
    int M)
{
    (void)M;
    __shared__ __bf16 sA[BM * BK];
    __shared__ __bf16 sB[BN * BK];

    const int tid = threadIdx.x;
    const int wv  = tid >> 6;
    const int l   = tid & 63;
    const int wy  = wv >> 1, wx = wv & 1;
    const int bm  = blockIdx.y * BM;
    const int bn  = blockIdx.x * BN;
    const int n   = l & 15;
    const int q   = l >> 4;

    const int srow  = l >> 3;
    const int skoff = (l & 7) * 8;

    f32x4 acc[4][4];
    #pragma unroll
    for (int mt = 0; mt < 4; ++mt)
        #pragma unroll
        for (int nt = 0; nt < 4; ++nt)
            acc[mt][nt] = (f32x4){0.f, 0.f, 0.f, 0.f};

    for (int kt = 0; kt < D_DIM / BK; ++kt) {
        const int k0 = kt * BK;
        #pragma unroll
        for (int j = 0; j < 4; ++j) {
            const int rbase = (j * 4 + wv) * 8;
            const __bf16* ga = A + (long)(bm + rbase + srow) * D_DIM + k0 + skoff;
            const __bf16* gb = W + (long)(bn + rbase + srow) * D_DIM + k0 + skoff;
            __builtin_amdgcn_global_load_lds(
                (const __attribute__((address_space(1))) void*)ga,
                (__attribute__((address_space(3))) void*)(sA + rbase * BK), 16, 0, 0);
            __builtin_amdgcn_global_load_lds(
                (const __attribute__((address_space(1))) void*)gb,
                (__attribute__((address_space(3))) void*)(sB + rbase * BK), 16, 0, 0);
        }
        __syncthreads();

        #pragma unroll
        for (int ks = 0; ks < 2; ++ks) {
            bf16x8 af[4], bfr[4];
            #pragma unroll
            for (int mt = 0; mt < 4; ++mt) {
                int row = wy * 64 + mt * 16 + n;
                af[mt] = *(const bf16x8*)(sA + row * BK + ks * 32 + q * 8);
            }
            #pragma unroll
            for (int nt = 0; nt < 4; ++nt) {
                int col = wx * 64 + nt * 16 + n;
                bfr[nt] = *(const bf16x8*)(sB + col * BK + ks * 32 + q * 8);
            }
            #pragma unroll
            for (int mt = 0; mt < 4; ++mt)
                #pragma unroll
                for (int nt = 0; nt < 4; ++nt)
                    acc[mt][nt] = __builtin_amdgcn_mfma_f32_16x16x32_bf16(
                        af[mt], bfr[nt], acc[mt][nt], 0, 0, 0);
        }
        __syncthreads();
    }

    #pragma unroll
    for (int nt = 0; nt < 4; ++nt) {
        int col = bn + wx * 64 + nt * 16 + n;
        float b = bias[col];
        #pragma unroll
        for (int mt = 0; mt < 4; ++mt) {
            #pragma unroll
            for (int r = 0; r < 4; ++r) {
                int row = bm + wy * 64 + mt * 16 + q * 4 + r;
                C[(long)row * G_DIM + col] = acc[mt][nt][r] + b;
            }
        }
    }
}

// ---------------------------------------------------------------------------
// Custom grid barrier: per-wg flag store-release + wave-0 cooperative poll.
// No atomic RMW contention: wg i writes flags[i]; wave 0 of each wg polls all
// 256 flags (lane j checks j, j+64, j+128, j+192 — contiguous, coalesced).
// Targets are monotone per step, so no flag reset is needed within a call.
// ---------------------------------------------------------------------------
__device__ __forceinline__ void grid_barrier(unsigned* __restrict__ flags,
                                             unsigned target, int tid, int wgid) {
    __syncthreads();                       // wg-local work for this step done
    if (tid == 0) {
        __builtin_amdgcn_fence(__ATOMIC_RELEASE, "agent");   // flush h writes
        __hip_atomic_store(&flags[wgid], target, __ATOMIC_RELAXED,
                           __HIP_MEMORY_SCOPE_AGENT);
    }
    if (tid < 64) {
        bool ok = false;
        while (!__all(ok)) {
            unsigned v0 = __hip_atomic_load(&flags[tid],       __ATOMIC_RELAXED, __HIP_MEMORY_SCOPE_AGENT);
            unsigned v1 = __hip_atomic_load(&flags[tid + 64],  __ATOMIC_RELAXED, __HIP_MEMORY_SCOPE_AGENT);
            unsigned v2 = __hip_atomic_load(&flags[tid + 128], __ATOMIC_RELAXED, __HIP_MEMORY_SCOPE_AGENT);
            unsigned v3 = __hip_atomic_load(&flags[tid + 192], __ATOMIC_RELAXED, __HIP_MEMORY_SCOPE_AGENT);
            ok = (v0 >= target) & (v1 >= target) & (v2 >= target) & (v3 >= target);
        }
    }
    __syncthreads();
    __builtin_amdgcn_fence(__ATOMIC_ACQUIRE, "agent");       // invalidate for h reads
}

// ---------------------------------------------------------------------------
// Phase 2: persistent scan. 256 wgs x 256 thr; wg owns 4 hidden units.
// Wh slice in registers; c/h_old carried in REGISTERS across steps (global
// cst/out only touched at chunk boundaries). One custom barrier per step;
// h double-buffered bf16 on step parity.
// ---------------------------------------------------------------------------
__global__ __launch_bounds__(256, 1) void lstm_scan_kernel(
    const __bf16* __restrict__ Whb,   // [4096][1024] bf16
    const float* __restrict__ xg,     // [tc][64][4096] fp32 (chunk-local)
    const float* __restrict__ mask,   // [512][64]
    float* __restrict__ cst,          // [64][1024] fp32 chunk-boundary state
    __bf16* __restrict__ hbuf,        // [2][64][1024] bf16 state
    float* __restrict__ out,          // [512][64][1024]
    unsigned* __restrict__ flags,     // [256] barrier flags
    int t0, int tc)
{
    __shared__ float sg[4][16 * 17];

    const int tid  = threadIdx.x;
    const int wgid = blockIdx.x;
    const int u0   = wgid * 4;
    const int wv   = tid >> 6;
    const int l    = tid & 63;
    const int n    = l & 15;
    const int q    = l >> 4;
    const int colg = ((n >> 2) << 10) + u0 + (n & 3);

    bf16x8 breg[32];
    {
        const __bf16* wrow = Whb + (long)colg * H_DIM + q * 8;
        #pragma unroll
        for (int ks = 0; ks < 32; ++ks)
            breg[ks] = *(const bf16x8*)(wrow + ks * 32);
    }

    const int rowA = wv * 16 + n;
    const int rloc = l >> 2;
    const int ui   = l & 3;
    const int rb   = wv * 16 + rloc;
    const int uu   = u0 + ui;

    // lane-owned recurrent state in registers
    float c_r, h_r;
    if (t0 == 0) { c_r = 0.0f; h_r = 0.0f; }
    else {
        c_r = cst[rb * H_DIM + uu];
        h_r = out[((long)(t0 - 1) * B_DIM + rb) * H_DIM + uu];
    }

    for (int t = 0; t < tc; ++t) {
        const int gt = t0 + t;
        const __bf16* hread = hbuf + (long)(gt & 1) * (B_DIM * H_DIM);
        __bf16* hwrite = hbuf + (long)((gt + 1) & 1) * (B_DIM * H_DIM);

        const float* xgrow = xg + ((long)t * B_DIM + rb) * G_DIM;
        float xgv0 = xgrow[uu];
        float xgv1 = xgrow[H_DIM + uu];
        float xgv2 = xgrow[2 * H_DIM + uu];
        float xgv3 = xgrow[3 * H_DIM + uu];
        float mk   = mask[gt * B_DIM + rb];

        const __bf16* hrow = hread + (long)rowA * H_DIM + q * 8;
        f32x4 ac0 = {0.f, 0.f, 0.f, 0.f};
        f32x4 ac1 = {0.f, 0.f, 0.f, 0.f};
        #pragma unroll
        for (int ks = 0; ks < 32; ks += 2) {
            bf16x8 a0 = *(const bf16x8*)(hrow + ks * 32);
            bf16x8 a1 = *(const bf16x8*)(hrow + (ks + 1) * 32);
            ac0 = __builtin_amdgcn_mfma_f32_16x16x32_bf16(a0, breg[ks],     ac0, 0, 0, 0);
            ac1 = __builtin_amdgcn_mfma_f32_16x16x32_bf16(a1, breg[ks + 1], ac1, 0, 0, 0);
        }
        f32x4 acc = ac0 + ac1;

        // gate exchange via per-wave LDS (same-wave write->read: no barrier)
        #pragma unroll
        for (int r = 0; r < 4; ++r)
            sg[wv][(q * 4 + r) * 17 + n] = acc[r];

        float ig = xgv0 + sg[wv][rloc * 17 + 0  + ui];
        float fg = xgv1 + sg[wv][rloc * 17 + 4  + ui];
        float og = xgv2 + sg[wv][rloc * 17 + 8  + ui];
        float gg = xgv3 + sg[wv][rloc * 17 + 12 + ui];

        float i_s = 1.0f / (1.0f + __expf(-ig));
        float f_s = 1.0f / (1.0f + __expf(-fg));
        float o_s = 1.0f / (1.0f + __expf(-og));
        float g_t = tanhf(gg);
        float c_new = f_s * c_r + i_s * g_t;
        float h_new = o_s * tanhf(c_new);
        float c_f = mk * c_new + (1.0f - mk) * c_r;
        float h_f = mk * h_new + (1.0f - mk) * h_r;
        c_r = c_f;
        h_r = h_f;

        hwrite[rb * H_DIM + uu] = (__bf16)h_f;
        out[((long)gt * B_DIM + rb) * H_DIM + uu] = h_f;
        if (t == tc - 1) cst[rb * H_DIM + uu] = c_f;

        grid_barrier(flags, (unsigned)(gt + 1), tid, wgid);
    }
}

// ---------------------------------------------------------------------------
// Host side. Workspace:
//   [Whb 8MiB][Wxb 8MiB][hbuf 256KiB x2? -> 2x128KiB][cst 256KiB][flags 1KiB]
//   (state block padded to 1 MiB) [xb chunk][xg chunk]
// ---------------------------------------------------------------------------
extern "C" void kernel_launch(void* const* d_in, const int* in_sizes, int n_in,
                              void* d_out, int out_size, void* d_ws, size_t ws_size,
                              hipStream_t stream)
{
    (void)in_sizes; (void)n_in; (void)out_size;
    const float* x     = (const float*)d_in[0];  // [512][64][1024]
    const float* xmask = (const float*)d_in[1];  // [512][64]
    const float* Wx    = (const float*)d_in[2];  // [4096][1024]
    const float* bx    = (const float*)d_in[3];  // [4096]
    const float* Wh    = (const float*)d_in[4];  // [4096][1024]
    float* out = (float*)d_out;

    char* ws = (char*)d_ws;
    __bf16*   Whb   = (__bf16*)(ws);
    __bf16*   Wxb   = (__bf16*)(ws + 8388608);
    __bf16*   hb    = (__bf16*)(ws + 16777216);             // 2 x 131072 B
    float*    cst   = (float*)(ws + 16777216 + 262144);     // 262144 B
    unsigned* flags = (unsigned*)(ws + 16777216 + 524288);  // 1024 B
    char* dyn = ws + 16777216 + 1048576;

    long avail = (long)ws_size - (16777216L + 1048576L);
    const long per_t = (long)B_DIM * D_DIM * 2 + (long)B_DIM * G_DIM * 4;
    long Tc = avail > 0 ? avail / per_t : 2;
    if (Tc > T_DIM) Tc = T_DIM;
    Tc &= ~1L;
    if (Tc < 2) Tc = 2;

    __bf16* xb = (__bf16*)dyn;
    float*  xg = (float*)(dyn + Tc * (long)B_DIM * D_DIM * 2);

    // zero h0 state + barrier flags (cst/c0 handled in-register by the kernel)
    hipMemsetAsync(ws + 16777216, 0, 1048576, stream);

    {
        long nw = (long)G_DIM * D_DIM;
        int nb = (int)(nw / 8 / 256);
        f32_to_bf16_kernel<<<nb, 256, 0, stream>>>(Wx, Wxb, nw);
        f32_to_bf16_kernel<<<nb, 256, 0, stream>>>(Wh, Whb, nw);
    }

    for (int t0 = 0; t0 < T_DIM; t0 += (int)Tc) {
        int tc = (int)((T_DIM - t0 < Tc) ? (long)(T_DIM - t0) : Tc);

        long nx = (long)tc * B_DIM * D_DIM;
        f32_to_bf16_kernel<<<(int)(nx / 8 / 256), 256, 0, stream>>>(
            x + (long)t0 * B_DIM * D_DIM, xb, nx);

        dim3 gg(G_DIM / BN, (tc * B_DIM) / BM);
        gemm_xg_kernel<<<gg, 256, 0, stream>>>(xb, Wxb, bx, xg, tc * B_DIM);

        const __bf16* Whb_a = Whb;
        const float*  xg_a  = xg;
        const float*  mask_a = xmask;
        float*  cst_a = cst;
        __bf16* hb_a  = hb;
        float*  out_a = out;
        unsigned* fl_a = flags;
        int t0_a = t0, tc_a = tc;
        void* args[] = {(void*)&Whb_a, (void*)&xg_a, (void*)&mask_a,
                        (void*)&cst_a, (void*)&hb_a, (void*)&out_a,
                        (void*)&fl_a, (void*)&t0_a, (void*)&tc_a};
        hipLaunchCooperativeKernel((void*)lstm_scan_kernel, dim3(NWG), dim3(256),
                                   args, 0, stream);
    }
}

// Round 3
// 7951.638 us; speedup vs baseline: 2.6849x; 1.5444x over previous
//
#include <hip/hip_runtime.h>
#include <hip/hip_bf16.h>

using f32x4  = __attribute__((ext_vector_type(4))) float;
using bf16x8 = __attribute__((ext_vector_type(8))) __bf16;
using u64    = unsigned long long;
using u64x2  = __attribute__((ext_vector_type(2))) u64;

#define T_DIM 512
#define B_DIM 64
#define D_DIM 1024
#define H_DIM 1024
#define G_DIM 4096   // 4*H
#define NWG   256    // workgroups in the scan kernel

// ---------------------------------------------------------------------------
// fp32 -> bf16 conversion (vectorized 8/thread)
// ---------------------------------------------------------------------------
__global__ void f32_to_bf16_kernel(const float* __restrict__ src,
                                   __bf16* __restrict__ dst, long n) {
    long i = ((long)blockIdx.x * blockDim.x + threadIdx.x) * 8;
    if (i + 8 <= n) {
        f32x4 a = *(const f32x4*)(src + i);
        f32x4 b = *(const f32x4*)(src + i + 4);
        bf16x8 o;
        o[0] = (__bf16)a[0]; o[1] = (__bf16)a[1];
        o[2] = (__bf16)a[2]; o[3] = (__bf16)a[3];
        o[4] = (__bf16)b[0]; o[5] = (__bf16)b[1];
        o[6] = (__bf16)b[2]; o[7] = (__bf16)b[3];
        *(bf16x8*)(dst + i) = o;
    }
}

// ---------------------------------------------------------------------------
// Phase 1: xg[M][4096] = A[M][1024](bf16) @ W[4096][1024]^T (bf16) + bias
// m97-style: 128x128 tile, BK=64, global_load_lds width=16, 16x16x32 bf16 MFMA.
// ---------------------------------------------------------------------------
#define BM 128
#define BN 128
#define BK 64

__global__ __launch_bounds__(256) void gemm_xg_kernel(
    const __bf16* __restrict__ A,    // [M][1024]
    const __bf16* __restrict__ W,    // [4096][1024]
    const float* __restrict__ bias,  // [4096]
    float* __restrict__ C,           // [M][4096]
    int M)
{
    (void)M;
    __shared__ __bf16 sA[BM * BK];
    __shared__ __bf16 sB[BN * BK];

    const int tid = threadIdx.x;
    const int wv  = tid >> 6;
    const int l   = tid & 63;
    const int wy  = wv >> 1, wx = wv & 1;
    const int bm  = blockIdx.y * BM;
    const int bn  = blockIdx.x * BN;
    const int n   = l & 15;
    const int q   = l >> 4;

    const int srow  = l >> 3;
    const int skoff = (l & 7) * 8;

    f32x4 acc[4][4];
    #pragma unroll
    for (int mt = 0; mt < 4; ++mt)
        #pragma unroll
        for (int nt = 0; nt < 4; ++nt)
            acc[mt][nt] = (f32x4){0.f, 0.f, 0.f, 0.f};

    for (int kt = 0; kt < D_DIM / BK; ++kt) {
        const int k0 = kt * BK;
        #pragma unroll
        for (int j = 0; j < 4; ++j) {
            const int rbase = (j * 4 + wv) * 8;
            const __bf16* ga = A + (long)(bm + rbase + srow) * D_DIM + k0 + skoff;
            const __bf16* gb = W + (long)(bn + rbase + srow) * D_DIM + k0 + skoff;
            __builtin_amdgcn_global_load_lds(
                (const __attribute__((address_space(1))) void*)ga,
                (__attribute__((address_space(3))) void*)(sA + rbase * BK), 16, 0, 0);
            __builtin_amdgcn_global_load_lds(
                (const __attribute__((address_space(1))) void*)gb,
                (__attribute__((address_space(3))) void*)(sB + rbase * BK), 16, 0, 0);
        }
        __syncthreads();

        #pragma unroll
        for (int ks = 0; ks < 2; ++ks) {
            bf16x8 af[4], bfr[4];
            #pragma unroll
            for (int mt = 0; mt < 4; ++mt) {
                int row = wy * 64 + mt * 16 + n;
                af[mt] = *(const bf16x8*)(sA + row * BK + ks * 32 + q * 8);
            }
            #pragma unroll
            for (int nt = 0; nt < 4; ++nt) {
                int col = wx * 64 + nt * 16 + n;
                bfr[nt] = *(const bf16x8*)(sB + col * BK + ks * 32 + q * 8);
            }
            #pragma unroll
            for (int mt = 0; mt < 4; ++mt)
                #pragma unroll
                for (int nt = 0; nt < 4; ++nt)
                    acc[mt][nt] = __builtin_amdgcn_mfma_f32_16x16x32_bf16(
                        af[mt], bfr[nt], acc[mt][nt], 0, 0, 0);
        }
        __syncthreads();
    }

    #pragma unroll
    for (int nt = 0; nt < 4; ++nt) {
        int col = bn + wx * 64 + nt * 16 + n;
        float b = bias[col];
        #pragma unroll
        for (int mt = 0; mt < 4; ++mt) {
            #pragma unroll
            for (int r = 0; r < 4; ++r) {
                int row = bm + wy * 64 + mt * 16 + q * 4 + r;
                C[(long)row * G_DIM + col] = acc[mt][nt][r] + b;
            }
        }
    }
}

// ---------------------------------------------------------------------------
// Fence-free grid barrier.
// All shared scan state (h, flags) moves via relaxed AGENT-scope atomics
// (sc0 sc1: write-through to / read-through from MALL, bypassing the
// non-coherent per-XCD L2s). Therefore NO cache-flush fences are needed:
// __syncthreads() drains vmcnt(0) in every wave, which completes the
// write-through h stores (globally visible) before tid 0 publishes the flag.
// ---------------------------------------------------------------------------
__device__ __forceinline__ void grid_barrier(unsigned* __restrict__ flags,
                                             unsigned target, int tid, int wgid) {
    __syncthreads();   // all waves: vmcnt(0) -> h stores visible at MALL
    if (tid == 0)
        __hip_atomic_store(&flags[wgid], target, __ATOMIC_RELAXED,
                           __HIP_MEMORY_SCOPE_AGENT);
    if (tid < 64) {
        bool ok = false;
        while (!__all(ok)) {
            unsigned v0 = __hip_atomic_load(&flags[tid],       __ATOMIC_RELAXED, __HIP_MEMORY_SCOPE_AGENT);
            unsigned v1 = __hip_atomic_load(&flags[tid + 64],  __ATOMIC_RELAXED, __HIP_MEMORY_SCOPE_AGENT);
            unsigned v2 = __hip_atomic_load(&flags[tid + 128], __ATOMIC_RELAXED, __HIP_MEMORY_SCOPE_AGENT);
            unsigned v3 = __hip_atomic_load(&flags[tid + 192], __ATOMIC_RELAXED, __HIP_MEMORY_SCOPE_AGENT);
            ok = (v0 >= target) & (v1 >= target) & (v2 >= target) & (v3 >= target);
        }
    }
    __syncthreads();
    __atomic_signal_fence(__ATOMIC_ACQUIRE);   // compiler-only: keep h loads after poll
}

// ---------------------------------------------------------------------------
// Phase 2: persistent scan. 256 wgs x 256 thr; wg owns 4 hidden units.
// Wh slice in registers; c/h_old in registers across steps. h exchanged
// through MALL via relaxed agent atomics; xg/mask/out stay normally cached
// (their L2 lines now SURVIVE across steps — no invalidation).
// ---------------------------------------------------------------------------
__global__ __launch_bounds__(256, 1) void lstm_scan_kernel(
    const __bf16* __restrict__ Whb,   // [4096][1024] bf16
    const float* __restrict__ xg,     // [tc][64][4096] fp32 (chunk-local)
    const float* __restrict__ mask,   // [512][64]
    float* __restrict__ cst,          // [64][1024] fp32 chunk-boundary state
    __bf16* __restrict__ hbuf,        // [2][64][1024] bf16 state
    float* __restrict__ out,          // [512][64][1024]
    unsigned* __restrict__ flags,     // [256] barrier flags
    int t0, int tc)
{
    __shared__ float sg[4][16 * 17];

    const int tid  = threadIdx.x;
    const int wgid = blockIdx.x;
    const int u0   = wgid * 4;
    const int wv   = tid >> 6;
    const int l    = tid & 63;
    const int n    = l & 15;
    const int q    = l >> 4;
    const int colg = ((n >> 2) << 10) + u0 + (n & 3);

    bf16x8 breg[32];
    {
        const __bf16* wrow = Whb + (long)colg * H_DIM + q * 8;
        #pragma unroll
        for (int ks = 0; ks < 32; ++ks)
            breg[ks] = *(const bf16x8*)(wrow + ks * 32);
    }

    const int rowA = wv * 16 + n;
    const int rloc = l >> 2;
    const int ui   = l & 3;
    const int rb   = wv * 16 + rloc;
    const int uu   = u0 + ui;

    float c_r, h_r;
    if (t0 == 0) { c_r = 0.0f; h_r = 0.0f; }
    else {
        c_r = cst[rb * H_DIM + uu];
        h_r = out[((long)(t0 - 1) * B_DIM + rb) * H_DIM + uu];
    }

    for (int t = 0; t < tc; ++t) {
        const int gt = t0 + t;
        const __bf16* hread = hbuf + (long)(gt & 1) * (B_DIM * H_DIM);
        __bf16* hwrite = hbuf + (long)((gt + 1) & 1) * (B_DIM * H_DIM);

        const float* xgrow = xg + ((long)t * B_DIM + rb) * G_DIM;
        float xgv0 = xgrow[uu];
        float xgv1 = xgrow[H_DIM + uu];
        float xgv2 = xgrow[2 * H_DIM + uu];
        float xgv3 = xgrow[3 * H_DIM + uu];
        float mk   = mask[gt * B_DIM + rb];

        // preload ALL h fragments (coherent MALL reads), then one MFMA burst
        u64* h64 = (u64*)(hread + (long)rowA * H_DIM);
        bf16x8 areg[32];
        #pragma unroll
        for (int ks = 0; ks < 32; ++ks) {
            u64x2 tt;
            tt.x = __hip_atomic_load(h64 + ks * 8 + q * 2,     __ATOMIC_RELAXED, __HIP_MEMORY_SCOPE_AGENT);
            tt.y = __hip_atomic_load(h64 + ks * 8 + q * 2 + 1, __ATOMIC_RELAXED, __HIP_MEMORY_SCOPE_AGENT);
            areg[ks] = __builtin_bit_cast(bf16x8, tt);
        }

        f32x4 ac0 = {0.f, 0.f, 0.f, 0.f};
        f32x4 ac1 = {0.f, 0.f, 0.f, 0.f};
        #pragma unroll
        for (int ks = 0; ks < 32; ks += 2) {
            ac0 = __builtin_amdgcn_mfma_f32_16x16x32_bf16(areg[ks],     breg[ks],     ac0, 0, 0, 0);
            ac1 = __builtin_amdgcn_mfma_f32_16x16x32_bf16(areg[ks + 1], breg[ks + 1], ac1, 0, 0, 0);
        }
        f32x4 acc = ac0 + ac1;

        // gate exchange via per-wave LDS (same-wave write->read)
        #pragma unroll
        for (int r = 0; r < 4; ++r)
            sg[wv][(q * 4 + r) * 17 + n] = acc[r];

        float ig = xgv0 + sg[wv][rloc * 17 + 0  + ui];
        float fg = xgv1 + sg[wv][rloc * 17 + 4  + ui];
        float og = xgv2 + sg[wv][rloc * 17 + 8  + ui];
        float gg = xgv3 + sg[wv][rloc * 17 + 12 + ui];

        float i_s = 1.0f / (1.0f + __expf(-ig));
        float f_s = 1.0f / (1.0f + __expf(-fg));
        float o_s = 1.0f / (1.0f + __expf(-og));
        float g_t = tanhf(gg);
        float c_new = f_s * c_r + i_s * g_t;
        float h_new = o_s * tanhf(c_new);
        float c_f = mk * c_new + (1.0f - mk) * c_r;
        float h_f = mk * h_new + (1.0f - mk) * h_r;
        c_r = c_f;
        h_r = h_f;

        // write-through h store (visible at MALL once vmcnt retires)
        unsigned short hsb = __builtin_bit_cast(unsigned short, (__bf16)h_f);
        __hip_atomic_store((unsigned short*)hwrite + (long)rb * H_DIM + uu, hsb,
                           __ATOMIC_RELAXED, __HIP_MEMORY_SCOPE_AGENT);
        out[((long)gt * B_DIM + rb) * H_DIM + uu] = h_f;
        if (t == tc - 1) cst[rb * H_DIM + uu] = c_f;

        grid_barrier(flags, (unsigned)(gt + 1), tid, wgid);
    }
}

// ---------------------------------------------------------------------------
// Host side. Workspace:
//   [Whb 8MiB][Wxb 8MiB][hbuf 2x128KiB][cst 256KiB][flags 1KiB] (pad to 1MiB)
//   [xb chunk][xg chunk]
// ---------------------------------------------------------------------------
extern "C" void kernel_launch(void* const* d_in, const int* in_sizes, int n_in,
                              void* d_out, int out_size, void* d_ws, size_t ws_size,
                              hipStream_t stream)
{
    (void)in_sizes; (void)n_in; (void)out_size;
    const float* x     = (const float*)d_in[0];  // [512][64][1024]
    const float* xmask = (const float*)d_in[1];  // [512][64]
    const float* Wx    = (const float*)d_in[2];  // [4096][1024]
    const float* bx    = (const float*)d_in[3];  // [4096]
    const float* Wh    = (const float*)d_in[4];  // [4096][1024]
    float* out = (float*)d_out;

    char* ws = (char*)d_ws;
    __bf16*   Whb   = (__bf16*)(ws);
    __bf16*   Wxb   = (__bf16*)(ws + 8388608);
    __bf16*   hb    = (__bf16*)(ws + 16777216);             // 2 x 131072 B
    float*    cst   = (float*)(ws + 16777216 + 262144);     // 262144 B
    unsigned* flags = (unsigned*)(ws + 16777216 + 524288);  // 1024 B
    char* dyn = ws + 16777216 + 1048576;

    long avail = (long)ws_size - (16777216L + 1048576L);
    const long per_t = (long)B_DIM * D_DIM * 2 + (long)B_DIM * G_DIM * 4;
    long Tc = avail > 0 ? avail / per_t : 2;
    if (Tc > T_DIM) Tc = T_DIM;
    Tc &= ~1L;
    if (Tc < 2) Tc = 2;

    __bf16* xb = (__bf16*)dyn;
    float*  xg = (float*)(dyn + Tc * (long)B_DIM * D_DIM * 2);

    // zero h0 state + barrier flags
    hipMemsetAsync(ws + 16777216, 0, 1048576, stream);

    {
        long nw = (long)G_DIM * D_DIM;
        int nb = (int)(nw / 8 / 256);
        f32_to_bf16_kernel<<<nb, 256, 0, stream>>>(Wx, Wxb, nw);
        f32_to_bf16_kernel<<<nb, 256, 0, stream>>>(Wh, Whb, nw);
    }

    for (int t0 = 0; t0 < T_DIM; t0 += (int)Tc) {
        int tc = (int)((T_DIM - t0 < Tc) ? (long)(T_DIM - t0) : Tc);

        long nx = (long)tc * B_DIM * D_DIM;
        f32_to_bf16_kernel<<<(int)(nx / 8 / 256), 256, 0, stream>>>(
            x + (long)t0 * B_DIM * D_DIM, xb, nx);

        dim3 gg(G_DIM / BN, (tc * B_DIM) / BM);
        gemm_xg_kernel<<<gg, 256, 0, stream>>>(xb, Wxb, bx, xg, tc * B_DIM);

        const __bf16* Whb_a = Whb;
        const float*  xg_a  = xg;
        const float*  mask_a = xmask;
        float*  cst_a = cst;
        __bf16* hb_a  = hb;
        float*  out_a = out;
        unsigned* fl_a = flags;
        int t0_a = t0, tc_a = tc;
        void* args[] = {(void*)&Whb_a, (void*)&xg_a, (void*)&mask_a,
                        (void*)&cst_a, (void*)&hb_a, (void*)&out_a,
                        (void*)&fl_a, (void*)&t0_a, (void*)&tc_a};
        hipLaunchCooperativeKernel((void*)lstm_scan_kernel, dim3(NWG), dim3(256),
                                   args, 0, stream);
    }
}